// Round 6
// baseline (138.254 us; speedup 1.0000x reference)
//
#include <hip/hip_runtime.h>
#include <hip/hip_fp16.h>
#include <cstddef>
#include <cstdint>

// Sinkformer attention, B=2 H=12 S=1024 D=64, fp32 in/out.
// Flash-recompute Sinkhorn: P = exp(QK^T/8) is NEVER materialized. Each pass
// recomputes P tiles via mfma_f32_16x16x32_f16 (128 FLOP/elem ~ 0.3 byte-equiv
// at machine balance, 6x cheaper than re-reading 2B of stored fp16 P).
//   rd0 = rowsum(P)                  -> a1 = mu/rd0
//   cs0 = colsum(P^T a1)             -> b1 = nu/cs0
//   rd1 = P b1                       -> a2 = mu/rd1
//   cs1 = colsum(P^T a2)             -> b2 = nu/cs1
//   rd2 = P b2                       -> a3 = mu/rd2
//   cs2 = colsum(P^T a3)             -> b3 = nu/cs2
//   attn = P * a3 * (1/cs2)  [b3*S = 1/cs2];  out = attn @ V.
// All reciprocal finalizes inlined at point of use (mu = nu = 1/1024).

#define NH 24
#define SEQ 1024
#define HD 64
#define NHS (NH * SEQ)

typedef _Float16 f16x8 __attribute__((ext_vector_type(8)));
typedef float f32x4 __attribute__((ext_vector_type(4)));

// zero rd0..cs2 (6*NHS contiguous floats)
__global__ __launch_bounds__(256) void k_init(float* __restrict__ z) {
  z[blockIdx.x * 256 + threadIdx.x] = 0.f;
}

// Recompute-P sweep. 128x128 tile per block, 4 waves of 64x64.
// MODE 0: rdOut_i += sum_j P_ij                    (b = 1)
// MODE 1: rdOut_i += sum_j P_ij * b_j,  b = (1/1024)/vecPrev[col]
// MODE 2: csOut_j += sum_i P_ij * a_i,  a = (1/1024)/vecPrev[row]
// grid: 1536 1-D, XCD-swizzled (192 consecutive swz ids = 3 whole heads/XCD).
template <int MODE>
__global__ __launch_bounds__(256) void k_sweep(const float* __restrict__ q,
                                               const float* __restrict__ kin,
                                               const float* __restrict__ vecPrev,
                                               float* __restrict__ vecOut) {
  __shared__ __align__(16) __half qs[128][72];
  __shared__ __align__(16) __half ks[128][72];
  __shared__ float ws_[128];

  const int bid = blockIdx.x;
  const int swz = (bid & 7) * 192 + (bid >> 3);   // 1536 % 8 == 0: bijective
  const int h = swz >> 6;
  const int row0 = ((swz >> 3) & 7) << 7;
  const int col0 = (swz & 7) << 7;
  const float* qh = q + (size_t)h * SEQ * HD;
  const float* kh = kin + (size_t)h * SEQ * HD;
  const int t = threadIdx.x;

#pragma unroll
  for (int it = 0; it < 8; ++it) {
    int f = t + (it << 8);
    int r = f >> 4, c4 = (f & 15) << 2;
    float4 v = *(const float4*)(qh + (size_t)(row0 + r) * HD + c4);
    *(__half2*)&qs[r][c4] = __floats2half2_rn(v.x, v.y);
    *(__half2*)&qs[r][c4 + 2] = __floats2half2_rn(v.z, v.w);
    float4 u = *(const float4*)(kh + (size_t)(col0 + r) * HD + c4);
    *(__half2*)&ks[r][c4] = __floats2half2_rn(u.x, u.y);
    *(__half2*)&ks[r][c4 + 2] = __floats2half2_rn(u.z, u.w);
  }
  if (MODE == 1 && t < 128) ws_[t] = (1.0f / 1024.0f) / vecPrev[h * SEQ + col0 + t];
  if (MODE == 2 && t < 128) ws_[t] = (1.0f / 1024.0f) / vecPrev[h * SEQ + row0 + t];
  __syncthreads();

  const int w = t >> 6, lane = t & 63;
  const int ln = lane & 15, ko = lane >> 4;
  const int rb = (w & 1) << 6, cb = (w >> 1) << 6;  // wave sub-tile 64x64
  f32x4 acc[4][4] = {};
#pragma unroll
  for (int kk = 0; kk < 2; ++kk) {
    f16x8 af[4], bf[4];
#pragma unroll
    for (int m = 0; m < 4; ++m)
      af[m] = *(const f16x8*)&qs[rb + m * 16 + ln][(kk << 5) + (ko << 3)];
#pragma unroll
    for (int n = 0; n < 4; ++n)
      bf[n] = *(const f16x8*)&ks[cb + n * 16 + ln][(kk << 5) + (ko << 3)];
#pragma unroll
    for (int m = 0; m < 4; ++m)
#pragma unroll
      for (int n = 0; n < 4; ++n)
        acc[m][n] = __builtin_amdgcn_mfma_f32_16x16x32_f16(af[m], bf[n], acc[m][n], 0, 0, 0);
  }

  // P = exp(score/8), in-register
#pragma unroll
  for (int m = 0; m < 4; ++m)
#pragma unroll
    for (int n = 0; n < 4; ++n)
#pragma unroll
      for (int r = 0; r < 4; ++r)
        acc[m][n][r] = __expf(acc[m][n][r] * 0.125f);

  if (MODE == 2) {
    // col reduce: element (row = rb+m*16+ko*4+r, col = cb+n*16+ln)
    float* cs = vecOut + h * SEQ;
#pragma unroll
    for (int n = 0; n < 4; ++n) {
      float s = 0.f;
#pragma unroll
      for (int m = 0; m < 4; ++m)
#pragma unroll
        for (int r = 0; r < 4; ++r)
          s += acc[m][n][r] * ws_[rb + m * 16 + (ko << 2) + r];
      s += __shfl_xor(s, 16);
      s += __shfl_xor(s, 32);
      if (lane < 16) atomicAdd(&cs[col0 + cb + n * 16 + ln], s);
    }
  } else {
    // row reduce
    float* rd = vecOut + h * SEQ;
#pragma unroll
    for (int m = 0; m < 4; ++m)
#pragma unroll
      for (int r = 0; r < 4; ++r) {
        float s;
        if (MODE == 1) {
          s = acc[m][0][r] * ws_[cb + ln] + acc[m][1][r] * ws_[cb + 16 + ln]
            + acc[m][2][r] * ws_[cb + 32 + ln] + acc[m][3][r] * ws_[cb + 48 + ln];
        } else {
          s = acc[m][0][r] + acc[m][1][r] + acc[m][2][r] + acc[m][3][r];
        }
        s += __shfl_xor(s, 1, 16); s += __shfl_xor(s, 2, 16);
        s += __shfl_xor(s, 4, 16); s += __shfl_xor(s, 8, 16);
        if (ln == 0) atomicAdd(&rd[row0 + rb + m * 16 + (ko << 2) + r], s);
      }
  }
}

// Final pass: recompute P strip (32 rows x 1024, in 8 chunks of 128 cols),
// attn = P * a3 * (1/cs2) written fp32 (LDS-staged, coalesced), PV via MFMA.
// grid: 768 1-D, XCD-swizzled (96 consecutive swz = 3 heads/XCD).
__global__ __launch_bounds__(256) void k_final(const float* __restrict__ q,
                                               const float* __restrict__ kin,
                                               const float* __restrict__ vin,
                                               const float* __restrict__ rd2,
                                               const float* __restrict__ cs2,
                                               float* __restrict__ attn,
                                               float* __restrict__ out) {
  __shared__ __align__(16) __half qs[32][72];
  __shared__ __align__(16) __half ks[128][72];
  __shared__ __align__(16) __half vt[64][136];    // V^T chunk: vt[d][j]
  __shared__ __align__(16) __half ps16[32][136];  // attn subtile fp16
  __shared__ float binv[128];
  __shared__ float a_s[32];

  const int bid = blockIdx.x;
  const int swz = (bid & 7) * 96 + (bid >> 3);    // 768 % 8 == 0: bijective
  const int h = swz >> 5;
  const int rblk = swz & 31;
  const int grow0 = h * SEQ + (rblk << 5);        // global row base
  const float* qh = q + (size_t)h * SEQ * HD;
  const float* kh = kin + (size_t)h * SEQ * HD;
  const float* Vh = vin + (size_t)h * SEQ * HD;
  const int t = threadIdx.x;
  const int w = t >> 6, lane = t & 63, ln = lane & 15, ko = lane >> 4;

  // stage Q strip (32x64) fp16 + a3
#pragma unroll
  for (int it = 0; it < 2; ++it) {
    int f = t + (it << 8);
    int r = f >> 4, c4 = (f & 15) << 2;
    float4 v = *(const float4*)(qh + (size_t)((rblk << 5) + r) * HD + c4);
    *(__half2*)&qs[r][c4] = __floats2half2_rn(v.x, v.y);
    *(__half2*)&qs[r][c4 + 2] = __floats2half2_rn(v.z, v.w);
  }
  if (t < 32) a_s[t] = (1.0f / 1024.0f) / rd2[grow0 + t];

  f32x4 acc_o[2] = {};  // wave: rows (w&1)*16, d-cols (w>>1)*32 (2 d-tiles)

  for (int c = 0; c < 8; ++c) {
    const int j0 = c << 7;
    __syncthreads();  // prior-iter readers of ks/vt/ps16/binv done (iter0: qs/a_s ready)
    // stage K chunk (128x64) row-major fp16
#pragma unroll
    for (int it = 0; it < 8; ++it) {
      int f = t + (it << 8);
      int j = f >> 4, c4 = (f & 15) << 2;
      float4 u = *(const float4*)(kh + (size_t)(j0 + j) * HD + c4);
      *(__half2*)&ks[j][c4] = __floats2half2_rn(u.x, u.y);
      *(__half2*)&ks[j][c4 + 2] = __floats2half2_rn(u.z, u.w);
    }
    // stage V chunk transposed: vt[d][j]; lane j = t&63 -> conflict-free LDS writes
#pragma unroll
    for (int it = 0; it < 4; ++it) {
      int c4 = (w << 2) + (it << 4);
      int j = t & 63;
      float4 v0 = *(const float4*)(Vh + (size_t)(j0 + j) * HD + c4);
      vt[c4 + 0][j] = __float2half(v0.x);
      vt[c4 + 1][j] = __float2half(v0.y);
      vt[c4 + 2][j] = __float2half(v0.z);
      vt[c4 + 3][j] = __float2half(v0.w);
      float4 v1 = *(const float4*)(Vh + (size_t)(j0 + 64 + j) * HD + c4);
      vt[c4 + 0][64 + j] = __float2half(v1.x);
      vt[c4 + 1][64 + j] = __float2half(v1.y);
      vt[c4 + 2][64 + j] = __float2half(v1.z);
      vt[c4 + 3][64 + j] = __float2half(v1.w);
    }
    if (t < 128) binv[t] = 1.0f / cs2[h * SEQ + j0 + t];
    __syncthreads();

    // QK^T for this wave's 32-col slice: cols cw..cw+31
    const int cw = w << 5;
    f32x4 acc[2][2] = {};
#pragma unroll
    for (int kk = 0; kk < 2; ++kk) {
      f16x8 af[2], bf[2];
#pragma unroll
      for (int m = 0; m < 2; ++m)
        af[m] = *(const f16x8*)&qs[m * 16 + ln][(kk << 5) + (ko << 3)];
#pragma unroll
      for (int n = 0; n < 2; ++n)
        bf[n] = *(const f16x8*)&ks[cw + n * 16 + ln][(kk << 5) + (ko << 3)];
#pragma unroll
      for (int m = 0; m < 2; ++m)
#pragma unroll
        for (int n = 0; n < 2; ++n)
          acc[m][n] = __builtin_amdgcn_mfma_f32_16x16x32_f16(af[m], bf[n], acc[m][n], 0, 0, 0);
    }
    // attn subtile -> ps16 (C-frag: row = m*16+ko*4+r, col = cw+n*16+ln)
#pragma unroll
    for (int m = 0; m < 2; ++m)
#pragma unroll
      for (int n = 0; n < 2; ++n)
#pragma unroll
        for (int r = 0; r < 4; ++r) {
          int row = m * 16 + (ko << 2) + r;
          int col = cw + n * 16 + ln;
          float av = __expf(acc[m][n][r] * 0.125f) * a_s[row] * binv[col];
          ps16[row][col] = __float2half(av);
        }
    __syncthreads();

    // attn global write: thread t covers row t>>3, 16 cols at (t&7)*16
    {
      int row = t >> 3, cg = (t & 7) << 4;
      f16x8 h0 = *(const f16x8*)&ps16[row][cg];
      f16x8 h1 = *(const f16x8*)&ps16[row][cg + 8];
      float* ap = attn + (size_t)(grow0 + row) * SEQ + j0 + cg;
      float4 o0 = make_float4((float)h0[0], (float)h0[1], (float)h0[2], (float)h0[3]);
      float4 o1 = make_float4((float)h0[4], (float)h0[5], (float)h0[6], (float)h0[7]);
      float4 o2 = make_float4((float)h1[0], (float)h1[1], (float)h1[2], (float)h1[3]);
      float4 o3 = make_float4((float)h1[4], (float)h1[5], (float)h1[6], (float)h1[7]);
      *(float4*)ap = o0; *(float4*)(ap + 4) = o1;
      *(float4*)(ap + 8) = o2; *(float4*)(ap + 12) = o3;
    }
    // PV accumulate: k-dim = this chunk's 128 cols (4 slices of 32)
#pragma unroll
    for (int ks_ = 0; ks_ < 4; ++ks_) {
      f16x8 a = *(const f16x8*)&ps16[((w & 1) << 4) + ln][(ks_ << 5) + (ko << 3)];
#pragma unroll
      for (int dt = 0; dt < 2; ++dt) {
        f16x8 b = *(const f16x8*)&vt[((w >> 1) << 5) + dt * 16 + ln][(ks_ << 5) + (ko << 3)];
        acc_o[dt] = __builtin_amdgcn_mfma_f32_16x16x32_f16(a, b, acc_o[dt], 0, 0, 0);
      }
    }
  }

#pragma unroll
  for (int dt = 0; dt < 2; ++dt)
#pragma unroll
    for (int r = 0; r < 4; ++r) {
      int row = grow0 + ((w & 1) << 4) + (ko << 2) + r;
      int d = ((w >> 1) << 5) + dt * 16 + ln;
      out[(size_t)row * HD + d] = acc_o[dt][r];
    }
}

extern "C" void kernel_launch(void* const* d_in, const int* in_sizes, int n_in,
                              void* d_out, int out_size, void* d_ws, size_t ws_size,
                              hipStream_t stream) {
  const float* q = (const float*)d_in[0];
  const float* k = (const float*)d_in[1];
  const float* v = (const float*)d_in[2];
  (void)in_sizes; (void)n_in; (void)out_size; (void)ws_size;  // mask is all-False

  float* out = (float*)d_out;
  float* attn = out + (size_t)NH * SEQ * HD;  // second tuple output

  float* wsf = (float*)d_ws;   // needs only 6*NHS floats (~590 KB)
  float* rd0 = wsf;
  float* cs0 = wsf + 1 * NHS;
  float* rd1 = wsf + 2 * NHS;
  float* cs1 = wsf + 3 * NHS;
  float* rd2 = wsf + 4 * NHS;
  float* cs2 = wsf + 5 * NHS;

  k_init<<<6 * NHS / 256, 256, 0, stream>>>(wsf);
  k_sweep<0><<<1536, 256, 0, stream>>>(q, k, rd0, rd0);   // rd0 = rowsum(P)
  k_sweep<2><<<1536, 256, 0, stream>>>(q, k, rd0, cs0);   // cs0 = colsum(P^T a1)
  k_sweep<1><<<1536, 256, 0, stream>>>(q, k, cs0, rd1);   // rd1 = P b1
  k_sweep<2><<<1536, 256, 0, stream>>>(q, k, rd1, cs1);   // cs1 = colsum(P^T a2)
  k_sweep<1><<<1536, 256, 0, stream>>>(q, k, cs1, rd2);   // rd2 = P b2
  k_sweep<2><<<1536, 256, 0, stream>>>(q, k, rd2, cs2);   // cs2 = colsum(P^T a3)
  k_final<<<768, 256, 0, stream>>>(q, k, v, rd2, cs2, attn, out);
}